// Round 12
// baseline (35.687 us; speedup 1.0000x reference)
//
#include <hip/hip_runtime.h>

#define NB 8
#define NP 16
#define NS 256
#define NN 4096
#define NBP (NB*NP)             // 128
#define NCHUNK 8
#define CHUNK (NN/NCHUNK)       // 512 n per block
#define NBLK (NBP*NCHUNK)       // 1024
#define EPSV 1e-6f

typedef _Float16 half8  __attribute__((ext_vector_type(8)));
typedef float    f32x16 __attribute__((ext_vector_type(16)));

#define H0 ((_Float16)0.0f)
#define H1 ((_Float16)1.0f)

// ---------------- workspace layout (bytes) ----------------
// minw : float[NBLK*NS]  @ 0          (1 MB)
// part : float[NBLK]     @ 0x100000
// s2p  : float[NBP]      @ 0x101000
// pp   : float[NBP]      @ 0x101200

// d2(s,n) = |a_s|^2 + |b_n|^2 - 2 a_s.b_n as a K=13 inner product (hi/lo f16
// splits, f32 accumulate -> ~1e-7 error; validated exact-pass in R11):
//   A row s : [xh,xh,xl,yh,yh,yl,zh,zh | zl,a2h,a2l,1,1,0,0,0]
//   B col n : [txh,txl,txh,tyh,tyl,tyh,tzh,tzl | tzh,1,1,b2h,b2l,0,0,0]
// mfma_f32_32x32x16_f16: A/B lane l holds row/col=l&31, k=(l>>5)*8+j.
// C/D: col=lane&31, row=(reg&3)+8*(reg>>2)+4*(lane>>5)  [m74/m101 verified]

__global__ __launch_bounds__(256) void sqreg_main(
    const float* __restrict__ sp,     // (B,P,S,3)
    const float* __restrict__ pts,    // (B,N,3)
    const float* __restrict__ assign, // (B,N,P)
    float* __restrict__ minw,         // (NBLK, S)
    float* __restrict__ partials)     // NBLK
{
    __shared__ __align__(16) _Float16 lsa[NS][16];     // 8 KB
    __shared__ __align__(16) _Float16 lpb[CHUNK][16];  // 16 KB
    __shared__ float pm1[4][CHUNK];                    // 8 KB
    __shared__ float psum[4];

    const int bid   = blockIdx.x;
    const int bp    = bid >> 3;
    const int chunk = bid & 7;
    const int p     = bp & 15;
    const int b     = bp >> 4;
    const int tid   = threadIdx.x;
    const int lane  = tid & 63;
    const int wave  = tid >> 6;
    const int l31   = lane & 31;
    const int hi    = lane >> 5;

    // ---- stage: f32 -> hi/lo f16 fragment rows ----
    {
        const float* s3 = sp + (size_t)(bp*NS)*3;
        float x = s3[tid*3+0], y = s3[tid*3+1], z = s3[tid*3+2];
        float a2 = x*x + y*y + z*z;
        _Float16 xh=(_Float16)x, yh=(_Float16)y, zh=(_Float16)z, ah=(_Float16)a2;
        _Float16 xl=(_Float16)(x-(float)xh), yl=(_Float16)(y-(float)yh);
        _Float16 zl=(_Float16)(z-(float)zh), al=(_Float16)(a2-(float)ah);
        half8 lo = {xh,xh,xl,yh,yh,yl,zh,zh};
        half8 hi8 = {zl,ah,al,H1,H1,H0,H0,H0};
        *(half8*)&lsa[tid][0] = lo;
        *(half8*)&lsa[tid][8] = hi8;

        const float* q3 = pts + (size_t)(b*NN + chunk*CHUNK)*3;
#pragma unroll
        for (int k = 0; k < 2; ++k) {
            int i = tid + k*256;
            float bx = q3[i*3+0], by = q3[i*3+1], bz = q3[i*3+2];
            float tx = -2.0f*bx, ty = -2.0f*by, tz = -2.0f*bz;
            float b2 = bx*bx + by*by + bz*bz;
            _Float16 txh=(_Float16)tx, tyh=(_Float16)ty, tzh=(_Float16)tz, bh=(_Float16)b2;
            _Float16 txl=(_Float16)(tx-(float)txh), tyl=(_Float16)(ty-(float)tyh);
            _Float16 tzl=(_Float16)(tz-(float)tzh), bl=(_Float16)(b2-(float)bh);
            half8 blo = {txh,txl,txh,tyh,tyl,tyh,tzh,tzl};
            half8 bhi = {tzh,H1,H1,bh,bl,H0,H0,H0};
            *(half8*)&lpb[i][0] = blo;
            *(half8*)&lpb[i][8] = bhi;
        }
    }
    __syncthreads();

    // ---- A fragments: wave owns s in [wave*64, wave*64+64) = 2 tiles of 32 ----
    half8 afrag[2];
#pragma unroll
    for (int st = 0; st < 2; ++st)
        afrag[st] = *(const half8*)&lsa[wave*64 + st*32 + l31][hi*8];

    f32x16 rmin0, rmin1;
#pragma unroll
    for (int r = 0; r < 16; ++r) { rmin0[r] = INFINITY; rmin1[r] = INFINITY; }

    // ---- MFMA sweep: 16 n-tiles x 2 s-tiles; both reductions from one tile ----
    for (int nt = 0; nt < 16; ++nt) {
        half8 bf = *(const half8*)&lpb[nt*32 + l31][hi*8];

        f32x16 a0 = __builtin_amdgcn_mfma_f32_32x32x16_f16(afrag[0], bf,
                        (f32x16)(0.0f), 0, 0, 0);
        f32x16 a1 = __builtin_amdgcn_mfma_f32_32x32x16_f16(afrag[1], bf,
                        (f32x16)(0.0f), 0, 0, 0);

        float cm = INFINITY;
#pragma unroll
        for (int r = 0; r < 16; ++r) {
            rmin0[r] = fminf(rmin0[r], a0[r]);
            rmin1[r] = fminf(rmin1[r], a1[r]);
            cm = fminf(cm, fminf(a0[r], a1[r]));
        }
        // cm = min over this lane's 32 s-rows; partner (lane^32) has the rest
        cm = fminf(cm, __shfl_xor(cm, 32, 64));
        pm1[wave][nt*32 + l31] = cm;   // both halves write same value/addr: benign
    }

    // ---- epilogue: min over n (fold 32 cols within each hi-group) -> minw ----
#pragma unroll
    for (int st = 0; st < 2; ++st) {
#pragma unroll
        for (int r = 0; r < 16; ++r) {
            float v = (st == 0) ? rmin0[r] : rmin1[r];
            v = fminf(v, __shfl_xor(v, 1, 64));
            v = fminf(v, __shfl_xor(v, 2, 64));
            v = fminf(v, __shfl_xor(v, 4, 64));
            v = fminf(v, __shfl_xor(v, 8, 64));
            v = fminf(v, __shfl_xor(v, 16, 64));
            if (l31 == 0) {
                int s = wave*64 + st*32 + (r & 3) + 8*(r >> 2) + 4*hi;
                minw[(size_t)bid*NS + s] = fmaxf(v, 0.0f);
            }
        }
    }
    __syncthreads();

    // ---- phase-1 combine: min over 4 waves' s-partials, weight, reduce ----
    float acc = 0.0f;
#pragma unroll
    for (int j = 0; j < 2; ++j) {
        int n = tid + j*256;
        float mm = fminf(fminf(pm1[0][n], pm1[1][n]),
                         fminf(pm1[2][n], pm1[3][n]));
        float d  = fmaxf(mm, 0.0f);
        acc += d * assign[(size_t)(b*NN + chunk*CHUNK + n)*NP + p];
    }
#pragma unroll
    for (int msk = 32; msk >= 1; msk >>= 1)
        acc += __shfl_xor(acc, msk, 64);
    if (lane == 0) psum[wave] = acc;
    __syncthreads();
    if (tid == 0) partials[bid] = psum[0] + psum[1] + psum[2] + psum[3];
}

__global__ __launch_bounds__(256) void sqreg_tail(
    const float* __restrict__ minw,     // (NBLK, S)
    const float* __restrict__ partials, // NBLK
    float* __restrict__ s2p,            // NBP
    float* __restrict__ pp)             // NBP
{
    __shared__ float wsum[4];
    const int bp   = blockIdx.x;
    const int tid  = threadIdx.x;
    const int lane = tid & 63;
    const int wave = tid >> 6;

    const float* base = minw + (size_t)(bp*NCHUNK)*NS + tid;
    float m = base[0];
#pragma unroll
    for (int c = 1; c < NCHUNK; ++c) m = fminf(m, base[(size_t)c*NS]);
#pragma unroll
    for (int msk = 32; msk >= 1; msk >>= 1)
        m += __shfl_xor(m, msk, 64);
    if (lane == 0) wsum[wave] = m;
    __syncthreads();

    if (tid == 0) {
        s2p[bp] = (wsum[0] + wsum[1] + wsum[2] + wsum[3]) * (1.0f/(float)NS);
        float a = 0.0f;
#pragma unroll
        for (int c = 0; c < NCHUNK; ++c) a += partials[bp*NCHUNK + c];
        pp[bp] = a;
    }
}

__global__ __launch_bounds__(256) void sqreg_final(
    const float* __restrict__ s2p,
    const float* __restrict__ pp,
    const float* __restrict__ exist,   // (B,P)
    float* __restrict__ out)
{
    __shared__ float ppw[2];
    __shared__ float fin[8];
    const int tid = threadIdx.x;

    float tsum = (tid < NBP) ? pp[tid] : 0.0f;
#pragma unroll
    for (int msk = 32; msk >= 1; msk >>= 1)
        tsum += __shfl_xor(tsum, msk, 64);
    if (tid == 0)  ppw[0] = tsum;
    if (tid == 64) ppw[1] = tsum;

    if (tid < NBP) {                   // group of 16 lanes = one b
        float e  = exist[tid];
        float sv = s2p[tid] * e;
#pragma unroll
        for (int msk = 8; msk >= 1; msk >>= 1) {
            e  += __shfl_xor(e,  msk, 64);
            sv += __shfl_xor(sv, msk, 64);
        }
        if ((tid & 15) == 0) fin[tid >> 4] = sv / fmaxf(e, EPSV);
    }
    __syncthreads();

    if (tid == 0) {
        float sq = 0.0f;
#pragma unroll
        for (int g = 0; g < NB; ++g) sq += fin[g];
        out[0] = (ppw[0] + ppw[1]) / (float)(NB*NN) + sq * (1.0f/(float)NB);
    }
}

extern "C" void kernel_launch(void* const* d_in, const int* in_sizes, int n_in,
                              void* d_out, int out_size, void* d_ws, size_t ws_size,
                              hipStream_t stream) {
    const float* sp     = (const float*)d_in[0];
    const float* pts    = (const float*)d_in[1];
    const float* assign = (const float*)d_in[2];
    const float* exist  = (const float*)d_in[3];
    float* out = (float*)d_out;

    char* ws = (char*)d_ws;
    float* minw = (float*)(ws);
    float* part = (float*)(ws + 0x100000);
    float* s2p  = (float*)(ws + 0x101000);
    float* pp   = (float*)(ws + 0x101200);

    sqreg_main <<<NBLK, 256, 0, stream>>>(sp, pts, assign, minw, part);
    sqreg_tail <<<NBP,  256, 0, stream>>>(minw, part, s2p, pp);
    sqreg_final<<<1,    256, 0, stream>>>(s2p, pp, exist, out);
}

// Round 13
// 28.015 us; speedup vs baseline: 1.2738x; 1.2738x over previous
//
#include <hip/hip_runtime.h>

#define NB 8
#define NP 16
#define NS 256
#define NN 4096
#define NBP (NB*NP)             // 128
#define NCHUNK 16
#define CHUNK (NN/NCHUNK)       // 256 n per block
#define NBLK (NBP*NCHUNK)       // 2048
#define EPSV 1e-6f

typedef _Float16 half8 __attribute__((ext_vector_type(8)));
typedef float    f32x4 __attribute__((ext_vector_type(4)));

#define H0 ((_Float16)0.0f)
#define H1 ((_Float16)1.0f)

// ---------------- workspace layout (bytes) ----------------
// minw : float[NBLK*NS]  @ 0          (2 MB)
// part : float[NBLK]     @ 0x200000   (8 KB)
// s2p  : float[NBP]      @ 0x202000
// pp   : float[NBP]      @ 0x202400

// d2(s,n) as K=13 f16 hi/lo-split inner product (validated exact in R11).
// Here A = points (rows = n), B = surface (cols = s):
//   A row n : [txh,txl,txh,tyh,tyl,tyh,tzh,tzl | tzh,1,1,b2h,b2l,0,0,0]
//   B col s : [xh,xh,xl,yh,yh,yl,zh,zh | zl,a2h,a2l,1,1,0,0,0]
// mfma_f32_16x16x32_f16: A/B lane l: row/col=l&15, k=(l>>4)*8+j (k>=16 zero here).
// C/D: col=lane&15 (s), row=(lane>>4)*4+reg (n)  [m89/m91 verified; R11 passed]

__global__ __launch_bounds__(256, 4) void sqreg_main(
    const float* __restrict__ sp,     // (B,P,S,3)
    const float* __restrict__ pts,    // (B,N,3)
    const float* __restrict__ assign, // (B,N,P)
    float* __restrict__ minw,         // (NBLK, S)
    float* __restrict__ partials)     // NBLK
{
    __shared__ __align__(16) _Float16 lsa[NS][16];     // surface frag rows (8 KB)
    __shared__ __align__(16) _Float16 lpb[CHUNK][16];  // point frag rows   (8 KB)
    __shared__ float pm1[CHUNK];                       // min_s d2 per n    (1 KB)
    __shared__ float pm2[4][NS];                       // per-wave min_n    (4 KB)
    __shared__ float psum[4];

    const int bid   = blockIdx.x;
    const int bp    = bid >> 4;
    const int chunk = bid & 15;
    const int p     = bp & 15;
    const int b     = bp >> 4;
    const int tid   = threadIdx.x;
    const int lane  = tid & 63;
    const int wave  = tid >> 6;
    const int l15   = lane & 15;

    // ---- stage: f32 -> hi/lo f16 fragment rows (1 s + 1 n per thread) ----
    {
        const float* s3 = sp + (size_t)(bp*NS)*3;
        float x = s3[tid*3+0], y = s3[tid*3+1], z = s3[tid*3+2];
        float a2 = x*x + y*y + z*z;
        _Float16 xh=(_Float16)x, yh=(_Float16)y, zh=(_Float16)z, ah=(_Float16)a2;
        _Float16 xl=(_Float16)(x-(float)xh), yl=(_Float16)(y-(float)yh);
        _Float16 zl=(_Float16)(z-(float)zh), al=(_Float16)(a2-(float)ah);
        half8 blo = {xh,xh,xl,yh,yh,yl,zh,zh};
        half8 bhi = {zl,ah,al,H1,H1,H0,H0,H0};
        *(half8*)&lsa[tid][0] = blo;
        *(half8*)&lsa[tid][8] = bhi;

        const float* q3 = pts + (size_t)(b*NN + chunk*CHUNK)*3;
        float bx = q3[tid*3+0], by = q3[tid*3+1], bz = q3[tid*3+2];
        float tx = -2.0f*bx, ty = -2.0f*by, tz = -2.0f*bz;
        float b2 = bx*bx + by*by + bz*bz;
        _Float16 txh=(_Float16)tx, tyh=(_Float16)ty, tzh=(_Float16)tz, bh=(_Float16)b2;
        _Float16 txl=(_Float16)(tx-(float)txh), tyl=(_Float16)(ty-(float)tyh);
        _Float16 tzl=(_Float16)(tz-(float)tzh), bl=(_Float16)(b2-(float)bh);
        half8 alo = {txh,txl,txh,tyh,tyl,tyh,tzh,tzl};
        half8 ahi = {tzh,H1,H1,bh,bl,H0,H0,H0};
        *(half8*)&lpb[tid][0] = alo;
        *(half8*)&lpb[tid][8] = ahi;
    }
    __syncthreads();

    // ---- A fragments: wave owns n in [wave*64, wave*64+64) = 4 tiles ----
    half8 afrag[4];
#pragma unroll
    for (int j = 0; j < 4; ++j) {
        half8 t = {H0,H0,H0,H0,H0,H0,H0,H0};
        if (lane < 32)
            t = *(const half8*)&lpb[wave*64 + j*16 + l15][(lane>>4)*8];
        afrag[j] = t;
    }

    f32x4 rp1[4];                      // phase-1: min over s, per n-tile rows
#pragma unroll
    for (int j = 0; j < 4; ++j) rp1[j] = (f32x4){INFINITY,INFINITY,INFINITY,INFINITY};
    float rp2[16];                     // phase-2: min over n, per s-tile (lane col)
#pragma unroll
    for (int st = 0; st < 16; ++st) rp2[st] = INFINITY;

    // ---- MFMA sweep: 16 s-tiles x 4 n-tiles; pure register reductions ----
#pragma unroll 4
    for (int st = 0; st < 16; ++st) {
        half8 bf = {H0,H0,H0,H0,H0,H0,H0,H0};
        if (lane < 32)
            bf = *(const half8*)&lsa[st*16 + l15][(lane>>4)*8];

        f32x4 acc[4];
#pragma unroll
        for (int j = 0; j < 4; ++j)
            acc[j] = __builtin_amdgcn_mfma_f32_16x16x32_f16(
                afrag[j], bf, (f32x4){0.f,0.f,0.f,0.f}, 0, 0, 0);

        float t0, t1;
#pragma unroll
        for (int j = 0; j < 4; ++j) {
            rp1[j][0] = fminf(rp1[j][0], acc[j][0]);
            rp1[j][1] = fminf(rp1[j][1], acc[j][1]);
            rp1[j][2] = fminf(rp1[j][2], acc[j][2]);
            rp1[j][3] = fminf(rp1[j][3], acc[j][3]);
        }
        t0 = fminf(fminf(acc[0][0], acc[0][1]), fminf(acc[0][2], acc[0][3]));
        t1 = fminf(fminf(acc[1][0], acc[1][1]), fminf(acc[1][2], acc[1][3]));
        t0 = fminf(t0, t1);
        t1 = fminf(fminf(acc[2][0], acc[2][1]), fminf(acc[2][2], acc[2][3]));
        t0 = fminf(t0, t1);
        t1 = fminf(fminf(acc[3][0], acc[3][1]), fminf(acc[3][2], acc[3][3]));
        rp2[st] = fminf(rp2[st], fminf(t0, t1));
    }

    // ---- epilogue phase 2: fold rowgroups, store per-wave col mins ----
#pragma unroll
    for (int st = 0; st < 16; ++st) {
        float v = rp2[st];
        v = fminf(v, __shfl_xor(v, 16, 64));
        v = fminf(v, __shfl_xor(v, 32, 64));
        pm2[wave][st*16 + l15] = v;    // 4 lanes same addr, same value: benign
    }

    // ---- epilogue phase 1: fold 16 cols, store min_s per n ----
#pragma unroll
    for (int j = 0; j < 4; ++j) {
#pragma unroll
        for (int r = 0; r < 4; ++r) {
            float v = rp1[j][r];
            v = fminf(v, __shfl_xor(v, 1, 64));
            v = fminf(v, __shfl_xor(v, 2, 64));
            v = fminf(v, __shfl_xor(v, 4, 64));
            v = fminf(v, __shfl_xor(v, 8, 64));
            pm1[wave*64 + j*16 + (lane>>4)*4 + r] = v;   // 16 lanes same addr: benign
        }
    }
    __syncthreads();

    // ---- combine: minw (s = tid) and weighted phase-1 sum (n = tid) ----
    {
        float mm = fminf(fminf(pm2[0][tid], pm2[1][tid]),
                         fminf(pm2[2][tid], pm2[3][tid]));
        minw[(size_t)bid*NS + tid] = fmaxf(mm, 0.0f);
    }
    float acc = fmaxf(pm1[tid], 0.0f) *
                assign[(size_t)(b*NN + chunk*CHUNK + tid)*NP + p];
#pragma unroll
    for (int msk = 32; msk >= 1; msk >>= 1)
        acc += __shfl_xor(acc, msk, 64);
    if ((tid & 63) == 0) psum[wave] = acc;
    __syncthreads();
    if (tid == 0) partials[bid] = psum[0] + psum[1] + psum[2] + psum[3];
}

__global__ __launch_bounds__(256) void sqreg_tail(
    const float* __restrict__ minw,     // (NBLK, S)
    const float* __restrict__ partials, // NBLK
    float* __restrict__ s2p,            // NBP
    float* __restrict__ pp)             // NBP
{
    __shared__ float wsum[4];
    const int bp   = blockIdx.x;
    const int tid  = threadIdx.x;
    const int lane = tid & 63;
    const int wave = tid >> 6;

    const float* base = minw + (size_t)(bp*NCHUNK)*NS + tid;
    float m = base[0];
#pragma unroll
    for (int c = 1; c < NCHUNK; ++c) m = fminf(m, base[(size_t)c*NS]);
#pragma unroll
    for (int msk = 32; msk >= 1; msk >>= 1)
        m += __shfl_xor(m, msk, 64);
    if (lane == 0) wsum[wave] = m;
    __syncthreads();

    if (tid == 0) {
        s2p[bp] = (wsum[0] + wsum[1] + wsum[2] + wsum[3]) * (1.0f/(float)NS);
        float a = 0.0f;
#pragma unroll
        for (int c = 0; c < NCHUNK; ++c) a += partials[bp*NCHUNK + c];
        pp[bp] = a;
    }
}

__global__ __launch_bounds__(256) void sqreg_final(
    const float* __restrict__ s2p,
    const float* __restrict__ pp,
    const float* __restrict__ exist,   // (B,P)
    float* __restrict__ out)
{
    __shared__ float ppw[2];
    __shared__ float fin[8];
    const int tid = threadIdx.x;

    float tsum = (tid < NBP) ? pp[tid] : 0.0f;
#pragma unroll
    for (int msk = 32; msk >= 1; msk >>= 1)
        tsum += __shfl_xor(tsum, msk, 64);
    if (tid == 0)  ppw[0] = tsum;
    if (tid == 64) ppw[1] = tsum;

    if (tid < NBP) {                   // group of 16 lanes = one b
        float e  = exist[tid];
        float sv = s2p[tid] * e;
#pragma unroll
        for (int msk = 8; msk >= 1; msk >>= 1) {
            e  += __shfl_xor(e,  msk, 64);
            sv += __shfl_xor(sv, msk, 64);
        }
        if ((tid & 15) == 0) fin[tid >> 4] = sv / fmaxf(e, EPSV);
    }
    __syncthreads();

    if (tid == 0) {
        float sq = 0.0f;
#pragma unroll
        for (int g = 0; g < NB; ++g) sq += fin[g];
        out[0] = (ppw[0] + ppw[1]) / (float)(NB*NN) + sq * (1.0f/(float)NB);
    }
}

extern "C" void kernel_launch(void* const* d_in, const int* in_sizes, int n_in,
                              void* d_out, int out_size, void* d_ws, size_t ws_size,
                              hipStream_t stream) {
    const float* sp     = (const float*)d_in[0];
    const float* pts    = (const float*)d_in[1];
    const float* assign = (const float*)d_in[2];
    const float* exist  = (const float*)d_in[3];
    float* out = (float*)d_out;

    char* ws = (char*)d_ws;
    float* minw = (float*)(ws);
    float* part = (float*)(ws + 0x200000);
    float* s2p  = (float*)(ws + 0x202000);
    float* pp   = (float*)(ws + 0x202400);

    sqreg_main <<<NBLK, 256, 0, stream>>>(sp, pts, assign, minw, part);
    sqreg_tail <<<NBP,  256, 0, stream>>>(minw, part, s2p, pp);
    sqreg_final<<<1,    256, 0, stream>>>(s2p, pp, exist, out);
}

// Round 14
// 25.252 us; speedup vs baseline: 1.4133x; 1.1094x over previous
//
#include <hip/hip_runtime.h>

#define NB 8
#define NP 16
#define NS 256
#define NN 4096
#define NBP (NB*NP)             // 128
#define NCHUNK 16
#define CHUNK (NN/NCHUNK)       // 256 n per block
#define NBLK (NBP*NCHUNK)       // 2048
#define EPSV 1e-6f

typedef _Float16 half8 __attribute__((ext_vector_type(8)));
typedef float    f32x4 __attribute__((ext_vector_type(4)));

#define H0 ((_Float16)0.0f)
#define H1 ((_Float16)1.0f)

// ---------------- workspace layout (bytes) ----------------
// minw : float[NBLK*NS]  @ 0          (2 MB)
// part : float[NBLK]     @ 0x200000   (8 KB)
// s2p  : float[NBP]      @ 0x202000
// pp   : float[NBP]      @ 0x202400

// d2(s,n) as K=13 f16 hi/lo-split inner product (validated exact R11/R13).
// A = points (rows = n), B = surface (cols = s); mfma_f32_16x16x32_f16.

__global__ __launch_bounds__(256, 4) void sqreg_main(
    const float* __restrict__ sp,     // (B,P,S,3)
    const float* __restrict__ pts,    // (B,N,3)
    const float* __restrict__ assign, // (B,N,P)
    float* __restrict__ minw,         // (NBLK, S)
    float* __restrict__ partials)     // NBLK
{
    // Overlay: staging fragments live during the MFMA loop; pm1t (phase-1
    // column-partial transpose buffer) reuses the same bytes afterwards,
    // separated by __syncthreads().
    __shared__ __align__(16) char smem[4*64*17*4];     // 17408 B
    _Float16 (*lsa)[16] = (_Float16(*)[16])smem;           // [NS][16] surface
    _Float16 (*lpb)[16] = (_Float16(*)[16])(smem + 8192);  // [CHUNK][16] points
    float    (*pm1t)[64][17] = (float(*)[64][17])smem;     // [4][64][17]
    __shared__ float pm2[4][NS];                       // per-wave min_n (4 KB)
    __shared__ float psum[4];

    const int bid   = blockIdx.x;
    const int bp    = bid >> 4;
    const int chunk = bid & 15;
    const int p     = bp & 15;
    const int b     = bp >> 4;
    const int tid   = threadIdx.x;
    const int lane  = tid & 63;
    const int wave  = tid >> 6;
    const int l15   = lane & 15;
    const int lg    = lane >> 4;

    // ---- stage: f32 -> hi/lo f16 fragment rows (1 s + 1 n per thread) ----
    {
        const float* s3 = sp + (size_t)(bp*NS)*3;
        float x = s3[tid*3+0], y = s3[tid*3+1], z = s3[tid*3+2];
        float a2 = x*x + y*y + z*z;
        _Float16 xh=(_Float16)x, yh=(_Float16)y, zh=(_Float16)z, ah=(_Float16)a2;
        _Float16 xl=(_Float16)(x-(float)xh), yl=(_Float16)(y-(float)yh);
        _Float16 zl=(_Float16)(z-(float)zh), al=(_Float16)(a2-(float)ah);
        half8 blo = {xh,xh,xl,yh,yh,yl,zh,zh};
        half8 bhi = {zl,ah,al,H1,H1,H0,H0,H0};
        *(half8*)&lsa[tid][0] = blo;
        *(half8*)&lsa[tid][8] = bhi;

        const float* q3 = pts + (size_t)(b*NN + chunk*CHUNK)*3;
        float bx = q3[tid*3+0], by = q3[tid*3+1], bz = q3[tid*3+2];
        float tx = -2.0f*bx, ty = -2.0f*by, tz = -2.0f*bz;
        float b2 = bx*bx + by*by + bz*bz;
        _Float16 txh=(_Float16)tx, tyh=(_Float16)ty, tzh=(_Float16)tz, bh=(_Float16)b2;
        _Float16 txl=(_Float16)(tx-(float)txh), tyl=(_Float16)(ty-(float)tyh);
        _Float16 tzl=(_Float16)(tz-(float)tzh), bl=(_Float16)(b2-(float)bh);
        half8 alo = {txh,txl,txh,tyh,tyl,tyh,tzh,tzl};
        half8 ahi = {tzh,H1,H1,bh,bl,H0,H0,H0};
        *(half8*)&lpb[tid][0] = alo;
        *(half8*)&lpb[tid][8] = ahi;
    }
    __syncthreads();

    // ---- A fragments: wave owns n in [wave*64, wave*64+64) = 4 tiles ----
    half8 afrag[4];
#pragma unroll
    for (int j = 0; j < 4; ++j) {
        half8 t = {H0,H0,H0,H0,H0,H0,H0,H0};
        if (lane < 32)
            t = *(const half8*)&lpb[wave*64 + j*16 + l15][(lane>>4)*8];
        afrag[j] = t;
    }

    f32x4 rp1[4];                      // phase-1: min over s (this lane's col set)
#pragma unroll
    for (int j = 0; j < 4; ++j) rp1[j] = (f32x4){INFINITY,INFINITY,INFINITY,INFINITY};
    float rp2[16];                     // phase-2: min over n, per s-tile (lane col)
#pragma unroll
    for (int st = 0; st < 16; ++st) rp2[st] = INFINITY;

    // ---- MFMA sweep: 16 s-tiles x 4 n-tiles; pure register reductions ----
#pragma unroll 4
    for (int st = 0; st < 16; ++st) {
        half8 bf = {H0,H0,H0,H0,H0,H0,H0,H0};
        if (lane < 32)
            bf = *(const half8*)&lsa[st*16 + l15][(lane>>4)*8];

        f32x4 acc[4];
#pragma unroll
        for (int j = 0; j < 4; ++j)
            acc[j] = __builtin_amdgcn_mfma_f32_16x16x32_f16(
                afrag[j], bf, (f32x4){0.f,0.f,0.f,0.f}, 0, 0, 0);

        float t0, t1;
#pragma unroll
        for (int j = 0; j < 4; ++j) {
            rp1[j][0] = fminf(rp1[j][0], acc[j][0]);
            rp1[j][1] = fminf(rp1[j][1], acc[j][1]);
            rp1[j][2] = fminf(rp1[j][2], acc[j][2]);
            rp1[j][3] = fminf(rp1[j][3], acc[j][3]);
        }
        t0 = fminf(fminf(acc[0][0], acc[0][1]), fminf(acc[0][2], acc[0][3]));
        t1 = fminf(fminf(acc[1][0], acc[1][1]), fminf(acc[1][2], acc[1][3]));
        t0 = fminf(t0, t1);
        t1 = fminf(fminf(acc[2][0], acc[2][1]), fminf(acc[2][2], acc[2][3]));
        t0 = fminf(t0, t1);
        t1 = fminf(fminf(acc[3][0], acc[3][1]), fminf(acc[3][2], acc[3][3]));
        rp2[st] = fminf(rp2[st], fminf(t0, t1));
    }

    __syncthreads();   // all waves done reading lsa/lpb -> overlay becomes valid

    // ---- epilogue phase 2: fold rowgroups via shfl, store per-wave col mins ----
#pragma unroll
    for (int st = 0; st < 16; ++st) {
        float v = rp2[st];
        v = fminf(v, __shfl_xor(v, 16, 64));
        v = fminf(v, __shfl_xor(v, 32, 64));
        pm2[wave][st*16 + l15] = v;    // 4 lanes same addr, same value: benign
    }

    // ---- epilogue phase 1: transpose col-partials into overlay LDS ----
#pragma unroll
    for (int j = 0; j < 4; ++j) {
#pragma unroll
        for (int r = 0; r < 4; ++r)
            pm1t[wave][j*16 + lg*4 + r][l15] = rp1[j][r];
    }
    __syncthreads();

    // ---- combine: minw (s = tid) and weighted phase-1 sum (n = tid) ----
    {
        float mm = fminf(fminf(pm2[0][tid], pm2[1][tid]),
                         fminf(pm2[2][tid], pm2[3][tid]));
        minw[(size_t)bid*NS + tid] = fmaxf(mm, 0.0f);
    }
    float acc;
    {
        const float* row = pm1t[tid >> 6][tid & 63];
        float m0 = fminf(fminf(row[0],  row[1]),  fminf(row[2],  row[3]));
        float m1 = fminf(fminf(row[4],  row[5]),  fminf(row[6],  row[7]));
        float m2 = fminf(fminf(row[8],  row[9]),  fminf(row[10], row[11]));
        float m3 = fminf(fminf(row[12], row[13]), fminf(row[14], row[15]));
        float mm = fminf(fminf(m0, m1), fminf(m2, m3));
        acc = fmaxf(mm, 0.0f) *
              assign[(size_t)(b*NN + chunk*CHUNK + tid)*NP + p];
    }
#pragma unroll
    for (int msk = 32; msk >= 1; msk >>= 1)
        acc += __shfl_xor(acc, msk, 64);
    if (lane == 0) psum[wave] = acc;
    __syncthreads();
    if (tid == 0) partials[bid] = psum[0] + psum[1] + psum[2] + psum[3];
}

__global__ __launch_bounds__(256) void sqreg_tail(
    const float* __restrict__ minw,     // (NBLK, S)
    const float* __restrict__ partials, // NBLK
    float* __restrict__ s2p,            // NBP
    float* __restrict__ pp)             // NBP
{
    __shared__ float wsum[4];
    const int bp   = blockIdx.x;
    const int tid  = threadIdx.x;
    const int lane = tid & 63;
    const int wave = tid >> 6;

    const float* base = minw + (size_t)(bp*NCHUNK)*NS + tid;
    float m = base[0];
#pragma unroll
    for (int c = 1; c < NCHUNK; ++c) m = fminf(m, base[(size_t)c*NS]);
#pragma unroll
    for (int msk = 32; msk >= 1; msk >>= 1)
        m += __shfl_xor(m, msk, 64);
    if (lane == 0) wsum[wave] = m;
    __syncthreads();

    if (tid == 0) {
        s2p[bp] = (wsum[0] + wsum[1] + wsum[2] + wsum[3]) * (1.0f/(float)NS);
        float a = 0.0f;
#pragma unroll
        for (int c = 0; c < NCHUNK; ++c) a += partials[bp*NCHUNK + c];
        pp[bp] = a;
    }
}

__global__ __launch_bounds__(256) void sqreg_final(
    const float* __restrict__ s2p,
    const float* __restrict__ pp,
    const float* __restrict__ exist,   // (B,P)
    float* __restrict__ out)
{
    __shared__ float ppw[2];
    __shared__ float fin[8];
    const int tid = threadIdx.x;

    float tsum = (tid < NBP) ? pp[tid] : 0.0f;
#pragma unroll
    for (int msk = 32; msk >= 1; msk >>= 1)
        tsum += __shfl_xor(tsum, msk, 64);
    if (tid == 0)  ppw[0] = tsum;
    if (tid == 64) ppw[1] = tsum;

    if (tid < NBP) {                   // group of 16 lanes = one b
        float e  = exist[tid];
        float sv = s2p[tid] * e;
#pragma unroll
        for (int msk = 8; msk >= 1; msk >>= 1) {
            e  += __shfl_xor(e,  msk, 64);
            sv += __shfl_xor(sv, msk, 64);
        }
        if ((tid & 15) == 0) fin[tid >> 4] = sv / fmaxf(e, EPSV);
    }
    __syncthreads();

    if (tid == 0) {
        float sq = 0.0f;
#pragma unroll
        for (int g = 0; g < NB; ++g) sq += fin[g];
        out[0] = (ppw[0] + ppw[1]) / (float)(NB*NN) + sq * (1.0f/(float)NB);
    }
}

extern "C" void kernel_launch(void* const* d_in, const int* in_sizes, int n_in,
                              void* d_out, int out_size, void* d_ws, size_t ws_size,
                              hipStream_t stream) {
    const float* sp     = (const float*)d_in[0];
    const float* pts    = (const float*)d_in[1];
    const float* assign = (const float*)d_in[2];
    const float* exist  = (const float*)d_in[3];
    float* out = (float*)d_out;

    char* ws = (char*)d_ws;
    float* minw = (float*)(ws);
    float* part = (float*)(ws + 0x200000);
    float* s2p  = (float*)(ws + 0x202000);
    float* pp   = (float*)(ws + 0x202400);

    sqreg_main <<<NBLK, 256, 0, stream>>>(sp, pts, assign, minw, part);
    sqreg_tail <<<NBP,  256, 0, stream>>>(minw, part, s2p, pp);
    sqreg_final<<<1,    256, 0, stream>>>(s2p, pp, exist, out);
}

// Round 15
// 24.675 us; speedup vs baseline: 1.4463x; 1.0234x over previous
//
#include <hip/hip_runtime.h>

#define NB 8
#define NP 16
#define NS 256
#define NN 4096
#define NBP (NB*NP)             // 128
#define NCHUNK 8
#define CHUNK (NN/NCHUNK)       // 512 n per block
#define NBLK (NBP*NCHUNK)       // 1024
#define EPSV 1e-6f

typedef _Float16 half8 __attribute__((ext_vector_type(8)));
typedef float    f32x4 __attribute__((ext_vector_type(4)));

#define H0 ((_Float16)0.0f)
#define H1 ((_Float16)1.0f)

// ---------------- workspace layout (bytes) ----------------
// minw : float[NBP*NS*NCHUNK] @ 0          (1 MB)  layout [bp][s][chunk]
// part : float[NBLK]          @ 0x100000
// s2p  : float[NBP]           @ 0x101000
// pp   : float[NBP]           @ 0x101200

// d2(s,n) as K=13 f16 hi/lo-split inner product (exact-pass R11/R13/R14).
// A = points (rows = n), B = surface (cols = s); mfma_f32_16x16x32_f16.
// A/B lane l: row/col=l&15, k=(l>>4)*8+j (k>=16 zeroed). C/D: col=lane&15,
// row=(lane>>4)*4+reg.

__global__ __launch_bounds__(256, 4) void sqreg_main(
    const float* __restrict__ sp,     // (B,P,S,3)
    const float* __restrict__ pts,    // (B,N,3)
    const float* __restrict__ assign, // (B,N,P)
    float* __restrict__ minw,         // [bp][s][chunk]
    float* __restrict__ partials)     // NBLK
{
    // Overlay: staging fragments (24 KB) live during the MFMA loop; pm1t
    // ([4][128][17] floats = 34816 B) reuses the bytes after a barrier.
    __shared__ __align__(16) char smem[4*128*17*4];
    _Float16 (*lsa)[16] = (_Float16(*)[16])smem;            // [NS][16] surface
    _Float16 (*lpb)[16] = (_Float16(*)[16])(smem + 8192);   // [CHUNK][16] points
    float    (*pm1t)[128][17] = (float(*)[128][17])smem;    // [4][128][17]
    __shared__ float pm2[4][NS];                            // per-wave min_n
    __shared__ float psum[4];

    const int bid   = blockIdx.x;
    const int bp    = bid >> 3;
    const int chunk = bid & 7;
    const int p     = bp & 15;
    const int b     = bp >> 4;
    const int tid   = threadIdx.x;
    const int lane  = tid & 63;
    const int wave  = tid >> 6;
    const int l15   = lane & 15;
    const int lg    = lane >> 4;

    // ---- stage: f32 -> hi/lo f16 fragment rows (1 s + 2 n per thread) ----
    {
        const float* s3 = sp + (size_t)(bp*NS)*3;
        float x = s3[tid*3+0], y = s3[tid*3+1], z = s3[tid*3+2];
        float a2 = x*x + y*y + z*z;
        _Float16 xh=(_Float16)x, yh=(_Float16)y, zh=(_Float16)z, ah=(_Float16)a2;
        _Float16 xl=(_Float16)(x-(float)xh), yl=(_Float16)(y-(float)yh);
        _Float16 zl=(_Float16)(z-(float)zh), al=(_Float16)(a2-(float)ah);
        half8 blo = {xh,xh,xl,yh,yh,yl,zh,zh};
        half8 bhi = {zl,ah,al,H1,H1,H0,H0,H0};
        *(half8*)&lsa[tid][0] = blo;
        *(half8*)&lsa[tid][8] = bhi;

        const float* q3 = pts + (size_t)(b*NN + chunk*CHUNK)*3;
#pragma unroll
        for (int k = 0; k < 2; ++k) {
            int i = tid + k*256;
            float bx = q3[i*3+0], by = q3[i*3+1], bz = q3[i*3+2];
            float tx = -2.0f*bx, ty = -2.0f*by, tz = -2.0f*bz;
            float b2 = bx*bx + by*by + bz*bz;
            _Float16 txh=(_Float16)tx, tyh=(_Float16)ty, tzh=(_Float16)tz, bh=(_Float16)b2;
            _Float16 txl=(_Float16)(tx-(float)txh), tyl=(_Float16)(ty-(float)tyh);
            _Float16 tzl=(_Float16)(tz-(float)tzh), bl=(_Float16)(b2-(float)bh);
            half8 alo = {txh,txl,txh,tyh,tyl,tyh,tzh,tzl};
            half8 ahi = {tzh,H1,H1,bh,bl,H0,H0,H0};
            *(half8*)&lpb[i][0] = alo;
            *(half8*)&lpb[i][8] = ahi;
        }
    }
    __syncthreads();

    // ---- A fragments: wave owns n in [wave*128, wave*128+128) = 8 tiles ----
    half8 afrag[8];
#pragma unroll
    for (int j = 0; j < 8; ++j) {
        half8 t = {H0,H0,H0,H0,H0,H0,H0,H0};
        if (lane < 32)
            t = *(const half8*)&lpb[wave*128 + j*16 + l15][(lane>>4)*8];
        afrag[j] = t;
    }

    f32x4 rp1[8];                      // phase-1: min over s, per n-tile rows
#pragma unroll
    for (int j = 0; j < 8; ++j) rp1[j] = (f32x4){INFINITY,INFINITY,INFINITY,INFINITY};
    float rp2[16];                     // phase-2: min over n, per s-tile (lane col)
#pragma unroll
    for (int st = 0; st < 16; ++st) rp2[st] = INFINITY;

    // ---- MFMA sweep: 16 s-tiles x 8 n-tiles; pure register reductions ----
#pragma unroll 2
    for (int st = 0; st < 16; ++st) {
        half8 bf = {H0,H0,H0,H0,H0,H0,H0,H0};
        if (lane < 32)
            bf = *(const half8*)&lsa[st*16 + l15][(lane>>4)*8];

        float tmin = INFINITY;
#pragma unroll
        for (int j = 0; j < 8; ++j) {
            f32x4 acc = __builtin_amdgcn_mfma_f32_16x16x32_f16(
                afrag[j], bf, (f32x4){0.f,0.f,0.f,0.f}, 0, 0, 0);
            rp1[j][0] = fminf(rp1[j][0], acc[0]);
            rp1[j][1] = fminf(rp1[j][1], acc[1]);
            rp1[j][2] = fminf(rp1[j][2], acc[2]);
            rp1[j][3] = fminf(rp1[j][3], acc[3]);
            tmin = fminf(tmin, fminf(fminf(acc[0], acc[1]), fminf(acc[2], acc[3])));
        }
        rp2[st] = fminf(rp2[st], tmin);
    }

    __syncthreads();   // staging reads complete -> overlay becomes writable

    // ---- epilogue phase 2: fold rowgroups via shfl, store per-wave col mins ----
#pragma unroll
    for (int st = 0; st < 16; ++st) {
        float v = rp2[st];
        v = fminf(v, __shfl_xor(v, 16, 64));
        v = fminf(v, __shfl_xor(v, 32, 64));
        pm2[wave][st*16 + l15] = v;    // 4 lanes same addr/value: benign
    }

    // ---- epilogue phase 1: transpose col-partials into overlay LDS ----
#pragma unroll
    for (int j = 0; j < 8; ++j) {
#pragma unroll
        for (int r = 0; r < 4; ++r)
            pm1t[wave][j*16 + lg*4 + r][l15] = rp1[j][r];
    }
    __syncthreads();

    // ---- combine: minw (s = tid, transposed layout) + weighted phase-1 sum ----
    {
        float mm = fminf(fminf(pm2[0][tid], pm2[1][tid]),
                         fminf(pm2[2][tid], pm2[3][tid]));
        minw[(size_t)(bp*NS + tid)*NCHUNK + chunk] = fmaxf(mm, 0.0f);
    }
    float acc = 0.0f;
#pragma unroll
    for (int u = 0; u < 2; ++u) {
        int n = tid + u*256;
        const float* row = pm1t[n >> 7][n & 127];
        float m0 = fminf(fminf(row[0],  row[1]),  fminf(row[2],  row[3]));
        float m1 = fminf(fminf(row[4],  row[5]),  fminf(row[6],  row[7]));
        float m2 = fminf(fminf(row[8],  row[9]),  fminf(row[10], row[11]));
        float m3 = fminf(fminf(row[12], row[13]), fminf(row[14], row[15]));
        float mm = fminf(fminf(m0, m1), fminf(m2, m3));
        acc += fmaxf(mm, 0.0f) *
               assign[(size_t)(b*NN + chunk*CHUNK + n)*NP + p];
    }
#pragma unroll
    for (int msk = 32; msk >= 1; msk >>= 1)
        acc += __shfl_xor(acc, msk, 64);
    if (lane == 0) psum[wave] = acc;
    __syncthreads();
    if (tid == 0) partials[bid] = psum[0] + psum[1] + psum[2] + psum[3];
}

__global__ __launch_bounds__(256) void sqreg_tail(
    const float* __restrict__ minw,     // [bp][s][chunk]
    const float* __restrict__ partials, // NBLK
    float* __restrict__ s2p,            // NBP
    float* __restrict__ pp)             // NBP
{
    __shared__ float wsum[4];
    const int bp   = blockIdx.x;
    const int tid  = threadIdx.x;
    const int lane = tid & 63;
    const int wave = tid >> 6;

    // 8 chunk-values for s = tid are contiguous: two b128 loads
    const f32x4* base = (const f32x4*)(minw + (size_t)(bp*NS + tid)*NCHUNK);
    f32x4 v0 = base[0], v1 = base[1];
    float m = fminf(fminf(fminf(v0[0], v0[1]), fminf(v0[2], v0[3])),
                    fminf(fminf(v1[0], v1[1]), fminf(v1[2], v1[3])));
#pragma unroll
    for (int msk = 32; msk >= 1; msk >>= 1)
        m += __shfl_xor(m, msk, 64);
    if (lane == 0) wsum[wave] = m;
    __syncthreads();

    if (tid == 0) {
        s2p[bp] = (wsum[0] + wsum[1] + wsum[2] + wsum[3]) * (1.0f/(float)NS);
        float a = 0.0f;
#pragma unroll
        for (int c = 0; c < NCHUNK; ++c) a += partials[bp*NCHUNK + c];
        pp[bp] = a;
    }
}

__global__ __launch_bounds__(256) void sqreg_final(
    const float* __restrict__ s2p,
    const float* __restrict__ pp,
    const float* __restrict__ exist,   // (B,P)
    float* __restrict__ out)
{
    __shared__ float ppw[2];
    __shared__ float fin[8];
    const int tid = threadIdx.x;

    float tsum = (tid < NBP) ? pp[tid] : 0.0f;
#pragma unroll
    for (int msk = 32; msk >= 1; msk >>= 1)
        tsum += __shfl_xor(tsum, msk, 64);
    if (tid == 0)  ppw[0] = tsum;
    if (tid == 64) ppw[1] = tsum;

    if (tid < NBP) {                   // group of 16 lanes = one b
        float e  = exist[tid];
        float sv = s2p[tid] * e;
#pragma unroll
        for (int msk = 8; msk >= 1; msk >>= 1) {
            e  += __shfl_xor(e,  msk, 64);
            sv += __shfl_xor(sv, msk, 64);
        }
        if ((tid & 15) == 0) fin[tid >> 4] = sv / fmaxf(e, EPSV);
    }
    __syncthreads();

    if (tid == 0) {
        float sq = 0.0f;
#pragma unroll
        for (int g = 0; g < NB; ++g) sq += fin[g];
        out[0] = (ppw[0] + ppw[1]) / (float)(NB*NN) + sq * (1.0f/(float)NB);
    }
}

extern "C" void kernel_launch(void* const* d_in, const int* in_sizes, int n_in,
                              void* d_out, int out_size, void* d_ws, size_t ws_size,
                              hipStream_t stream) {
    const float* sp     = (const float*)d_in[0];
    const float* pts    = (const float*)d_in[1];
    const float* assign = (const float*)d_in[2];
    const float* exist  = (const float*)d_in[3];
    float* out = (float*)d_out;

    char* ws = (char*)d_ws;
    float* minw = (float*)(ws);
    float* part = (float*)(ws + 0x100000);
    float* s2p  = (float*)(ws + 0x101000);
    float* pp   = (float*)(ws + 0x101200);

    sqreg_main <<<NBLK, 256, 0, stream>>>(sp, pts, assign, minw, part);
    sqreg_tail <<<NBP,  256, 0, stream>>>(minw, part, s2p, pp);
    sqreg_final<<<1,    256, 0, stream>>>(s2p, pp, exist, out);
}